// Round 10
// baseline (175.732 us; speedup 1.0000x reference)
//
#include <hip/hip_runtime.h>

// ModulatedConv2d: B=16, IN=512, OUT=512, STYLE=512, K=3, H=W=32
// out[b,o] = scale[b,o] * conv2d(x[b,i]*s[b,i], W[o,i])   (shared weights!)
// Conv = one implicit GEMM: M=512 out-ch, N=16384 (b,px), K=9x512.
// x staged as zero-padded NHWC bf16 -> no boundary masking.
//
// R12: 128x128 blk, 4 waves 64x64 (ratio 0.5), dbuf, 2 blk/CU: 91.6us.
//      Step 3053cy = floor 2304 +32%.
// R13/R14: B direct-from-global: 160-162us (VMEM scatter). Dead.
// R15: raw lgkm barrier = R12 -> vmcnt drain not the cost.
// R16: 1 wave/SIMD: 133us. No co-resident work = stalls exposed.
// R17: 128x256 blk, 8 waves 2x2x2(kg), ratio 0.375, 1 blk/CU: 86.5us.
//      Step 2883cy = floor 1728 +67% -- single block pays huge overhead;
//      R12's 2-block overlap (m114) is what keeps +32%.
// R18 (this): ratio 0.375 AND 2 blk/CU. Block 128x128, 4 waves =
//      2(wm) x 2(kg), wave 64x128 x k-half: 12 reads/32 MFMA. SINGLE
//      buffer (32KB) + 2-barrier step (2nd barrier hidden by co-resident
//      block). Grid 4m x 128n = 512 = 2/CU. Staging = R12's proven code.
//      kg-merge epilogue via LDS reuse (2 rounds by wm).
//      Predict: conv 70-78us, MfmaUtil 40-46%, LDS 33.5KB, WRITE ~33MB
//      (spill tripwire). Fallback >=85us => geometry family exhausted.

#define BATCH   16
#define CIN     512
#define COUT    512
#define IMG     32
#define PAD_IMG 34

static constexpr float AFF_SCALE = 0.044194173824159216f;  // 1/sqrt(512)
static constexpr float W_SCALE   = 0.014731391274719739f;  // 1/sqrt(512*9)

typedef __bf16 bf16x8 __attribute__((ext_vector_type(8)));
typedef float  f32x4  __attribute__((ext_vector_type(4)));

__device__ inline unsigned short f2bf(float f) {
    union { float f; unsigned int u; } v; v.f = f;
    unsigned int u = v.u;
    unsigned int r = (u + 0x7FFFu + ((u >> 16) & 1u)) >> 16;
    return (unsigned short)r;
}

__device__ inline float waveReduceSum(float v) {
    #pragma unroll
    for (int off = 32; off > 0; off >>= 1) v += __shfl_xor(v, off, 64);
    return v;
}

// ---- kernel 1: fused prep ----
__global__ void prep1(const float* __restrict__ cw,
                      const float* __restrict__ style,
                      const float* __restrict__ aw,
                      const float* __restrict__ ab,
                      unsigned short* __restrict__ w_t,
                      float* __restrict__ wsq,
                      float* __restrict__ s_out) {
    const int tid = threadIdx.x;
    if (blockIdx.x < 1024) {
        __shared__ float wl[2304];
        const float* src = cw + (size_t)blockIdx.x * 2304;
        for (int j = tid; j < 2304; j += 256) wl[j] = src[j];
        __syncthreads();
        const int idx = blockIdx.x * 256 + tid;       // o*512 + i
        const int base = tid * 9;
        float acc = 0.f;
        #pragma unroll
        for (int e = 0; e < 9; ++e) {
            float v = wl[base + e];
            acc += v * v;
            w_t[e * (COUT * CIN) + idx] = f2bf(v);
        }
        wsq[idx] = acc;
    } else {
        const int q = blockIdx.x - 1024;              // 0..2047
        const int b = q >> 7;
        const int i = (q & 127) * 4 + (tid >> 6);
        const int lane = tid & 63;
        float sum = 0.f;
        #pragma unroll
        for (int k = 0; k < 512; k += 64)
            sum += style[b * 512 + k + lane] * aw[i * 512 + k + lane];
        sum = waveReduceSum(sum);
        if (lane == 0)
            s_out[b * 512 + i] = sum * AFF_SCALE + ab[i] + 1.0f;
    }
}

// ---- kernel 2: fused xpad + scale ----
__global__ void prep2(const float* __restrict__ x,
                      const float* __restrict__ s_in,
                      const float* __restrict__ wsq,
                      unsigned short* __restrict__ xpad,
                      float* __restrict__ scl) {
    const int tid = threadIdx.x;
    if (blockIdx.x >= 4352) {
        const int q = blockIdx.x - 4352;              // 0..2047
        const int b = q >> 7;                         // 0..15
        const int o = (q & 127) * 4 + (tid >> 6);     // 0..511
        const int lane = tid & 63;
        float sum = 0.f;
        #pragma unroll
        for (int i = 0; i < 512; i += 64) {
            float sv = s_in[b * 512 + i + lane];
            sum += sv * sv * wsq[o * 512 + i + lane];
        }
        sum = waveReduceSum(sum);
        if (lane == 0)
            scl[b * 512 + o] = W_SCALE * rsqrtf(W_SCALE * W_SCALE * sum + 1e-8f);
        return;
    }
    const int c0   = blockIdx.x & 7;                  // *64 channels
    const int rest = blockIdx.x >> 3;                 // 0..543
    const int hh   = rest % 34;
    const int b    = rest / 34;
    const int c0b  = c0 * 64;
    unsigned short* rowbase = xpad + (((size_t)b * PAD_IMG + hh) * PAD_IMG) * 512;

    if (hh == 0 || hh == PAD_IMG - 1) {
        for (int j = tid; j < 34 * 32; j += 256) {
            int ww = j >> 5, cp = (j & 31) * 2;
            *(unsigned int*)(rowbase + (size_t)ww * 512 + c0b + cp) = 0u;
        }
        return;
    }

    __shared__ float t[64][33];
    const int h = hh - 1;
    {
        const int wx = tid & 31;
        const int cb = (tid >> 5) * 8;
        const float* xb = x + (((size_t)b * 512 + c0b + cb) * IMG + h) * IMG + wx;
        #pragma unroll
        for (int j = 0; j < 8; ++j)
            t[cb + j][wx] = xb[(size_t)j * (IMG * IMG)] * s_in[b * 512 + c0b + cb + j];
    }
    __syncthreads();
    {
        const int p  = tid >> 3;
        const int cc = (tid & 7) * 8;
        unsigned short* dst = rowbase + (size_t)(p + 1) * 512 + c0b + cc;
        uint4 pk;
        pk.x = (unsigned)f2bf(t[cc + 0][p]) | ((unsigned)f2bf(t[cc + 1][p]) << 16);
        pk.y = (unsigned)f2bf(t[cc + 2][p]) | ((unsigned)f2bf(t[cc + 3][p]) << 16);
        pk.z = (unsigned)f2bf(t[cc + 4][p]) | ((unsigned)f2bf(t[cc + 5][p]) << 16);
        pk.w = (unsigned)f2bf(t[cc + 6][p]) | ((unsigned)f2bf(t[cc + 7][p]) << 16);
        *(uint4*)dst = pk;
    }
    if (tid < 64) {
        int ww = (tid >> 5) ? (PAD_IMG - 1) : 0;
        int cp = (tid & 31) * 2;
        *(unsigned int*)(rowbase + (size_t)ww * 512 + c0b + cp) = 0u;
    }
}

// ---- kernel 3: implicit-GEMM conv, 128x128 block, 4 waves (wm x kg) ----
// Wave tile 64(M) x 128(N) x k-half: 12 b128 reads / 32 MFMA = 0.375.
// Single LDS buffer (A 16KB + B 16KB), 2-barrier step; 2 blocks/CU hide
// each other's barrier/drain stalls. Reg-staged prefetch (R12's proven
// offsets/swizzle). grid 512 (XCD-swizzled), block 256.

#define SYNC() do {                                                           \
    asm volatile("s_waitcnt lgkmcnt(0)" ::: "memory");                        \
    __builtin_amdgcn_s_barrier();                                             \
    __builtin_amdgcn_sched_barrier(0);                                        \
} while (0)

// loader: step -> 8 named uint4 regs (A/B 128x64 slabs)  [R12-verbatim]
#define LOADSTEP(stp) do {                                                    \
    const int e_  = (stp) >> 3;                                               \
    const int kc_ = ((stp) & 7) << 6;                                         \
    const int kh_ = (e_ * 11) >> 5;                                           \
    const int kw_ = e_ - kh_ * 3;                                             \
    const unsigned short* Ab_ = wt + (size_t)e_ * (COUT * CIN)                \
                                   + (size_t)m0 * 512 + kc_;                  \
    const unsigned short* Bb_ = xpad + bImgBase                               \
                              + (size_t)((h0 + kh_) * PAD_IMG + kw_) * 512    \
                              + kc_;                                          \
    ra0 = *(const uint4*)(Ab_ + aOff0);                                       \
    ra1 = *(const uint4*)(Ab_ + aOff1);                                       \
    ra2 = *(const uint4*)(Ab_ + aOff2);                                       \
    ra3 = *(const uint4*)(Ab_ + aOff3);                                       \
    rb0 = *(const uint4*)(Bb_ + bOff0);                                       \
    rb1 = *(const uint4*)(Bb_ + bOff1);                                       \
    rb2 = *(const uint4*)(Bb_ + bOff2);                                       \
    rb3 = *(const uint4*)(Bb_ + bOff3);                                       \
} while (0)

#define COMMIT() do {                                                         \
    *(uint4*)(Alds + lOff0) = ra0;                                            \
    *(uint4*)(Alds + lOff1) = ra1;                                            \
    *(uint4*)(Alds + lOff2) = ra2;                                            \
    *(uint4*)(Alds + lOff3) = ra3;                                            \
    *(uint4*)(Blds + lOff0) = rb0;                                            \
    *(uint4*)(Blds + lOff1) = rb1;                                            \
    *(uint4*)(Blds + lOff2) = rb2;                                            \
    *(uint4*)(Blds + lOff3) = rb3;                                            \
} while (0)

__global__ __launch_bounds__(256, 2) void conv_mfma(
    const unsigned short* __restrict__ wt,    // [9][512][512] bf16
    const unsigned short* __restrict__ xpad,  // [16][34][34][512] bf16
    const float* __restrict__ scl,            // [16][512]
    float* __restrict__ out)                  // [16][512][32][32]
{
    // 32KB: A 16KB + B 16KB; epilogue reuses the whole thing as f32.
    __shared__ __align__(16) unsigned char smem[32768];
    unsigned short* Alds = (unsigned short*)smem;
    unsigned short* Blds = (unsigned short*)(smem + 16384);
    __shared__ float sclds[128];

    const int tid = threadIdx.x;
    // XCD swizzle: id&7 -> XCD. Each XCD: 16 (h,b)-pairs x 4 m-blocks.
    const int id    = blockIdx.x;
    const int xcd   = id & 7;
    const int local = id >> 3;                   // 0..63
    const int gp    = xcd * 16 + (local >> 2);   // 0..127  (h,b) pair
    const int m0  = (local & 3) * 128;
    const int h0  = (gp & 7) * 4;
    const int b   = gp >> 3;

    if (tid < 128) sclds[tid] = scl[b * 512 + m0 + tid];

    const int wid  = tid >> 6;
    const int lane = tid & 63;
    const int wm = wid & 1;                      // M half (64 rows)
    const int kg = wid >> 1;                     // k-group (k-half of step)

    const f32x4 vzero = {0.f, 0.f, 0.f, 0.f};
    f32x4 acc[4][8];
    #pragma unroll
    for (int i = 0; i < 4; ++i)
        #pragma unroll
        for (int j = 0; j < 8; ++j) acc[i][j] = vzero;

    // staging offsets [R12-verbatim]: thread f = r*256+tid owns
    // (row=f>>3, chunk c=f&7); XOR swizzle p = c ^ (row&7). Named scalars
    // (R9 SROA lesson).
    int aOff0, aOff1, aOff2, aOff3;
    int bOff0, bOff1, bOff2, bOff3;
    int lOff0, lOff1, lOff2, lOff3;
    {
        int f, row, c, p;
        f = tid;             row = f >> 3; c = f & 7; p = c ^ (row & 7);
        aOff0 = row * 512 + c * 8;
        bOff0 = ((row >> 5) * PAD_IMG + (row & 31)) * 512 + c * 8;
        lOff0 = row * 64 + p * 8;
        f = 256 + tid;       row = f >> 3; c = f & 7; p = c ^ (row & 7);
        aOff1 = row * 512 + c * 8;
        bOff1 = ((row >> 5) * PAD_IMG + (row & 31)) * 512 + c * 8;
        lOff1 = row * 64 + p * 8;
        f = 512 + tid;       row = f >> 3; c = f & 7; p = c ^ (row & 7);
        aOff2 = row * 512 + c * 8;
        bOff2 = ((row >> 5) * PAD_IMG + (row & 31)) * 512 + c * 8;
        lOff2 = row * 64 + p * 8;
        f = 768 + tid;       row = f >> 3; c = f & 7; p = c ^ (row & 7);
        aOff3 = row * 512 + c * 8;
        bOff3 = ((row >> 5) * PAD_IMG + (row & 31)) * 512 + c * 8;
        lOff3 = row * 64 + p * 8;
    }

    const size_t bImgBase = (size_t)b * PAD_IMG * PAD_IMG * 512;

    // prefetch state: 8 named uint4 scalars (SROA-safe)
    uint4 ra0, ra1, ra2, ra3, rb0, rb1, rb2, rb3;

    LOADSTEP(0);

    // fragment read addresses: this wave reads k-chunk q = kg*4+kch at
    // swizzled position q^(row&7); row&7 = rl&7 (wave bases %16==0).
    const int rl   = lane & 15;
    const int kch  = lane >> 4;                  // 0..3
    const int swz  = ((kg * 4 + kch) ^ (rl & 7)) * 8;
    const int arow = (wm * 64 + rl) * 64;
    const int brow = rl * 64;

    for (int step = 0; step < 72; ++step) {
        COMMIT();                 // vmcnt waits = loads issued last iter
        const int nxt = step + 1 < 72 ? step + 1 : 71;
        LOADSTEP(nxt);            // in flight across both barriers
        SYNC();                   // staging visible

        bf16x8 af[4], bfr[8];
        #pragma unroll
        for (int mi = 0; mi < 4; ++mi)
            af[mi] = *(const bf16x8*)(Alds + arow + mi * (16 * 64) + swz);
        #pragma unroll
        for (int ni = 0; ni < 8; ++ni)
            bfr[ni] = *(const bf16x8*)(Blds + brow + ni * (16 * 64) + swz);

        __builtin_amdgcn_s_setprio(1);
        #pragma unroll
        for (int mi = 0; mi < 4; ++mi)
            #pragma unroll
            for (int ni = 0; ni < 8; ++ni)
                acc[mi][ni] = __builtin_amdgcn_mfma_f32_16x16x32_bf16(
                    af[mi], bfr[ni], acc[mi][ni], 0, 0, 0);
        __builtin_amdgcn_s_setprio(0);

        SYNC();                   // all reads drained -> next COMMIT safe
        // (reads completed before MFMA consumed them; lgkmcnt(0) cheap)
    }

    // ---- epilogue: merge kg partials via LDS (2 rounds by wm) ----
    // C frag layout: col(N)=lane&15, row(M)=(lane>>4)*4+reg [m89-verified]
    const int colp = lane & 15;
    const int rowq = (lane >> 4) * 4;
    float* ep = (float*)smem;                    // 32KB as f32
    for (int wmr = 0; wmr < 2; ++wmr) {
        __syncthreads();
        if (wm == wmr && kg == 1) {
            #pragma unroll
            for (int mi = 0; mi < 4; ++mi)
                #pragma unroll
                for (int ni = 0; ni < 8; ++ni)
                    *(f32x4*)(ep + ((mi * 8 + ni) * 64 + lane) * 4) =
                        acc[mi][ni];
        }
        __syncthreads();
        if (wm == wmr && kg == 0) {
            #pragma unroll
            for (int mi = 0; mi < 4; ++mi) {
                #pragma unroll
                for (int ni = 0; ni < 8; ++ni) {
                    const f32x4 o =
                        *(const f32x4*)(ep + ((mi * 8 + ni) * 64 + lane) * 4);
                    const int p = h0 * 32 + ni * 16 + colp;
                    #pragma unroll
                    for (int r2 = 0; r2 < 4; ++r2) {
                        const int ol = wmr * 64 + mi * 16 + rowq + r2;
                        out[(((size_t)b * 512 + m0 + ol) << 10) + p] =
                            (acc[mi][ni][r2] + o[r2]) * sclds[ol];
                    }
                }
            }
        }
    }
}

extern "C" void kernel_launch(void* const* d_in, const int* in_sizes, int n_in,
                              void* d_out, int out_size, void* d_ws, size_t ws_size,
                              hipStream_t stream) {
    const float* x     = (const float*)d_in[0];  // [16,512,32,32]
    const float* style = (const float*)d_in[1];  // [16,512]
    const float* aw    = (const float*)d_in[2];  // [512,512]
    const float* ab    = (const float*)d_in[3];  // [512]
    const float* cw    = (const float*)d_in[4];  // [512,512,3,3]
    float* out = (float*)d_out;

    char* ws = (char*)d_ws;
    float* s_buf          = (float*)(ws);                      //  32 KB
    float* scl            = (float*)(ws + 32768);              //  32 KB
    float* wsq            = (float*)(ws + 65536);              //   1 MB
    unsigned short* w_t   = (unsigned short*)(ws + 1114112);   // 4.5 MB bf16
    unsigned short* x_pad = (unsigned short*)(ws + 5832704);   // 18.9 MB bf16
    // total ws need: 24,772,608 B

    prep1<<<dim3(3072), 256, 0, stream>>>(cw, style, aw, ab, w_t, wsq, s_buf);
    prep2<<<dim3(6400), 256, 0, stream>>>(x, s_buf, wsq, x_pad, scl);
    conv_mfma<<<dim3(512), 256, 0, stream>>>(w_t, x_pad, scl, out);
}

// Round 11
// 171.401 us; speedup vs baseline: 1.0253x; 1.0253x over previous
//
#include <hip/hip_runtime.h>

// ModulatedConv2d: B=16, IN=512, OUT=512, STYLE=512, K=3, H=W=32
// out[b,o] = scale[b,o] * conv2d(x[b,i]*s[b,i], W[o,i])   (shared weights!)
// Conv = one implicit GEMM: M=512 out-ch, N=16384 (b,px), K=9x512.
// x staged as zero-padded NHWC bf16 -> no boundary masking.
//
// R12: 128x128 blk, 4 waves 64x64, dbuf, 2 blk/CU: 91.6us.
// R13/R14: B direct-from-global: ~161us (VMEM scatter). Dead.
// R15: raw lgkm barrier = R12 -> vmcnt drain not the cost.
// R16: 1 wave/SIMD: 133us. R18: 0.375-ratio @ 2 blk/CU, 2-barrier: 90.3us.
// R17: 128x256 blk, 8 waves 2(wm)x2(wn)x2(kg), dbuf, 1 blk/CU: 86.5us BEST.
// MODEL (fits R12/R17/R18): time = LDS-time + MFMA-time SERIALLY -- no
//      pipe overlap in any config. Cause: mi-outer MFMA order makes the
//      first 8 MFMAs need ALL 8 B-frags -> every read must land before
//      MFMA starts; 96-read post-barrier burst runs with MFMA idle.
// R19 (this): R17 base + INCREMENTAL CONSUMPTION. Read af[0..3]+bfr[0],
//      then ni-outer: {issue read bfr[ni+1]; 4 MFMAs on bfr[ni]}. First
//      MFMA waits 5 reads; each later read (12cy) hides under a 4-MFMA
//      group (~78cy). Counted lgkmcnt does the rest. Everything else
//      R17-verbatim.
//      Predict: conv 65-75us MfmaUtil 45-52% if overlap lands; neutral
//      85-88 => scheduler already pipelined, pivot to prep/total.

#define BATCH   16
#define CIN     512
#define COUT    512
#define IMG     32
#define PAD_IMG 34

static constexpr float AFF_SCALE = 0.044194173824159216f;  // 1/sqrt(512)
static constexpr float W_SCALE   = 0.014731391274719739f;  // 1/sqrt(512*9)

typedef __bf16 bf16x8 __attribute__((ext_vector_type(8)));
typedef float  f32x4  __attribute__((ext_vector_type(4)));

__device__ inline unsigned short f2bf(float f) {
    union { float f; unsigned int u; } v; v.f = f;
    unsigned int u = v.u;
    unsigned int r = (u + 0x7FFFu + ((u >> 16) & 1u)) >> 16;
    return (unsigned short)r;
}

__device__ inline float waveReduceSum(float v) {
    #pragma unroll
    for (int off = 32; off > 0; off >>= 1) v += __shfl_xor(v, off, 64);
    return v;
}

// ---- kernel 1: fused prep ----
__global__ void prep1(const float* __restrict__ cw,
                      const float* __restrict__ style,
                      const float* __restrict__ aw,
                      const float* __restrict__ ab,
                      unsigned short* __restrict__ w_t,
                      float* __restrict__ wsq,
                      float* __restrict__ s_out) {
    const int tid = threadIdx.x;
    if (blockIdx.x < 1024) {
        __shared__ float wl[2304];
        const float* src = cw + (size_t)blockIdx.x * 2304;
        for (int j = tid; j < 2304; j += 256) wl[j] = src[j];
        __syncthreads();
        const int idx = blockIdx.x * 256 + tid;       // o*512 + i
        const int base = tid * 9;
        float acc = 0.f;
        #pragma unroll
        for (int e = 0; e < 9; ++e) {
            float v = wl[base + e];
            acc += v * v;
            w_t[e * (COUT * CIN) + idx] = f2bf(v);
        }
        wsq[idx] = acc;
    } else {
        const int q = blockIdx.x - 1024;              // 0..2047
        const int b = q >> 7;
        const int i = (q & 127) * 4 + (tid >> 6);
        const int lane = tid & 63;
        float sum = 0.f;
        #pragma unroll
        for (int k = 0; k < 512; k += 64)
            sum += style[b * 512 + k + lane] * aw[i * 512 + k + lane];
        sum = waveReduceSum(sum);
        if (lane == 0)
            s_out[b * 512 + i] = sum * AFF_SCALE + ab[i] + 1.0f;
    }
}

// ---- kernel 2: fused xpad + scale ----
__global__ void prep2(const float* __restrict__ x,
                      const float* __restrict__ s_in,
                      const float* __restrict__ wsq,
                      unsigned short* __restrict__ xpad,
                      float* __restrict__ scl) {
    const int tid = threadIdx.x;
    if (blockIdx.x >= 4352) {
        const int q = blockIdx.x - 4352;              // 0..2047
        const int b = q >> 7;                         // 0..15
        const int o = (q & 127) * 4 + (tid >> 6);     // 0..511
        const int lane = tid & 63;
        float sum = 0.f;
        #pragma unroll
        for (int i = 0; i < 512; i += 64) {
            float sv = s_in[b * 512 + i + lane];
            sum += sv * sv * wsq[o * 512 + i + lane];
        }
        sum = waveReduceSum(sum);
        if (lane == 0)
            scl[b * 512 + o] = W_SCALE * rsqrtf(W_SCALE * W_SCALE * sum + 1e-8f);
        return;
    }
    const int c0   = blockIdx.x & 7;                  // *64 channels
    const int rest = blockIdx.x >> 3;                 // 0..543
    const int hh   = rest % 34;
    const int b    = rest / 34;
    const int c0b  = c0 * 64;
    unsigned short* rowbase = xpad + (((size_t)b * PAD_IMG + hh) * PAD_IMG) * 512;

    if (hh == 0 || hh == PAD_IMG - 1) {
        for (int j = tid; j < 34 * 32; j += 256) {
            int ww = j >> 5, cp = (j & 31) * 2;
            *(unsigned int*)(rowbase + (size_t)ww * 512 + c0b + cp) = 0u;
        }
        return;
    }

    __shared__ float t[64][33];
    const int h = hh - 1;
    {
        const int wx = tid & 31;
        const int cb = (tid >> 5) * 8;
        const float* xb = x + (((size_t)b * 512 + c0b + cb) * IMG + h) * IMG + wx;
        #pragma unroll
        for (int j = 0; j < 8; ++j)
            t[cb + j][wx] = xb[(size_t)j * (IMG * IMG)] * s_in[b * 512 + c0b + cb + j];
    }
    __syncthreads();
    {
        const int p  = tid >> 3;
        const int cc = (tid & 7) * 8;
        unsigned short* dst = rowbase + (size_t)(p + 1) * 512 + c0b + cc;
        uint4 pk;
        pk.x = (unsigned)f2bf(t[cc + 0][p]) | ((unsigned)f2bf(t[cc + 1][p]) << 16);
        pk.y = (unsigned)f2bf(t[cc + 2][p]) | ((unsigned)f2bf(t[cc + 3][p]) << 16);
        pk.z = (unsigned)f2bf(t[cc + 4][p]) | ((unsigned)f2bf(t[cc + 5][p]) << 16);
        pk.w = (unsigned)f2bf(t[cc + 6][p]) | ((unsigned)f2bf(t[cc + 7][p]) << 16);
        *(uint4*)dst = pk;
    }
    if (tid < 64) {
        int ww = (tid >> 5) ? (PAD_IMG - 1) : 0;
        int cp = (tid & 31) * 2;
        *(unsigned int*)(rowbase + (size_t)ww * 512 + c0b + cp) = 0u;
    }
}

// ---- kernel 3: implicit-GEMM conv, 128x256 block, 8 waves, BK=64 ----
// Waves: wm=(wid>>1)&1, wn=wid&1, kg=wid>>2. Output wave tile 64x128;
// kg=0 does k0..31 of each step, kg=1 does k32..63 (partial acc, merged
// in epilogue via LDS). Reg-staged dbuf LDS (A 2x16KB, B 2x32KB), raw
// lgkm barrier, XOR swizzle. grid 256 (XCD-swizzled), 1 block/CU,
// 2 waves/SIMD. R19: incremental-consumption MFMA ordering (ni-outer,
// bfr reads interleaved between MFMA groups).

#define SYNC() do {                                                           \
    asm volatile("s_waitcnt lgkmcnt(0)" ::: "memory");                        \
    __builtin_amdgcn_s_barrier();                                             \
    __builtin_amdgcn_sched_barrier(0);                                        \
} while (0)

// loader: step -> 2 A regs (128x64 slab) + 4 B regs (256x64 slab)
#define LOADSTEP(stp) do {                                                    \
    const int e_  = (stp) >> 3;                                               \
    const int kc_ = ((stp) & 7) << 6;                                         \
    const int kh_ = (e_ * 11) >> 5;                                           \
    const int kw_ = e_ - kh_ * 3;                                             \
    const unsigned short* Ab_ = wt + (size_t)e_ * (COUT * CIN)                \
                                   + (size_t)m0 * 512 + kc_;                  \
    const unsigned short* Bb_ = xpad + bImgBase                               \
                              + (size_t)((h0 + kh_) * PAD_IMG + kw_) * 512    \
                              + kc_;                                          \
    ra0 = *(const uint4*)(Ab_ + aOff0);                                       \
    ra1 = *(const uint4*)(Ab_ + aOff1);                                       \
    rb0 = *(const uint4*)(Bb_ + bOff0);                                       \
    rb1 = *(const uint4*)(Bb_ + bOff1);                                       \
    rb2 = *(const uint4*)(Bb_ + bOff2);                                       \
    rb3 = *(const uint4*)(Bb_ + bOff3);                                       \
} while (0)

#define COMMIT(Albuf, Blbuf) do {                                             \
    *(uint4*)((Albuf) + lA0) = ra0;                                           \
    *(uint4*)((Albuf) + lA1) = ra1;                                           \
    *(uint4*)((Blbuf) + lB0) = rb0;                                           \
    *(uint4*)((Blbuf) + lB1) = rb1;                                           \
    *(uint4*)((Blbuf) + lB2) = rb2;                                           \
    *(uint4*)((Blbuf) + lB3) = rb3;                                           \
} while (0)

__global__ __launch_bounds__(512, 2) void conv_mfma(
    const unsigned short* __restrict__ wt,    // [9][512][512] bf16
    const unsigned short* __restrict__ xpad,  // [16][34][34][512] bf16
    const float* __restrict__ scl,            // [16][512]
    float* __restrict__ out)                  // [16][512][32][32]
{
    // 96KB carved: A dbuf 2x16KB, B dbuf 2x32KB; epilogue reuses as f32.
    __shared__ __align__(16) unsigned char smem[98304];
    unsigned short* Alds0 = (unsigned short*)(smem);
    unsigned short* Alds1 = (unsigned short*)(smem + 16384);
    unsigned short* Blds0 = (unsigned short*)(smem + 32768);
    unsigned short* Blds1 = (unsigned short*)(smem + 65536);
    __shared__ float sclds[128];

    const int tid = threadIdx.x;
    // XCD swizzle: 256 blocks, id&7 -> XCD. Per XCD: 8 N-blocks x 4 m.
    const int id    = blockIdx.x;
    const int xcd   = id & 7;
    const int local = id >> 3;                   // 0..31
    const int gp    = xcd * 8 + (local >> 2);    // 0..63  N-block (b, hg)
    const int m0  = (local & 3) * 128;
    const int b   = gp >> 2;                     // 0..15
    const int h0  = (gp & 3) * 8;                // 0,8,16,24

    if (tid < 128) sclds[tid] = scl[b * 512 + m0 + tid];

    const int wid  = tid >> 6;
    const int lane = tid & 63;
    const int wm = (wid >> 1) & 1;               // M half (64 rows)
    const int wn = wid & 1;                      // N half (128 px)
    const int kg = wid >> 2;                     // k-group (k-half of step)

    const f32x4 vzero = {0.f, 0.f, 0.f, 0.f};
    f32x4 acc[4][8];
    #pragma unroll
    for (int i = 0; i < 4; ++i)
        #pragma unroll
        for (int j = 0; j < 8; ++j) acc[i][j] = vzero;

    // staging offsets (named scalars -- R9 SROA lesson). 512 threads:
    // A: f = r*512+tid, r=0..1 -> rows 0..127, chunk c=f&7.
    // B: f = r*512+tid, r=0..3 -> rows 0..255 (px index in N-tile).
    // XOR swizzle p = c ^ (row&7).
    int aOff0, aOff1, lA0, lA1;
    int bOff0, bOff1, bOff2, bOff3, lB0, lB1, lB2, lB3;
    {
        int f, row, c, p;
        f = tid;              row = f >> 3; c = f & 7; p = c ^ (row & 7);
        aOff0 = row * 512 + c * 8;  lA0 = row * 64 + p * 8;
        f = 512 + tid;        row = f >> 3; c = f & 7; p = c ^ (row & 7);
        aOff1 = row * 512 + c * 8;  lA1 = row * 64 + p * 8;

        f = tid;              row = f >> 3; c = f & 7; p = c ^ (row & 7);
        bOff0 = ((row >> 5) * PAD_IMG + (row & 31)) * 512 + c * 8;
        lB0 = row * 64 + p * 8;
        f = 512 + tid;        row = f >> 3; c = f & 7; p = c ^ (row & 7);
        bOff1 = ((row >> 5) * PAD_IMG + (row & 31)) * 512 + c * 8;
        lB1 = row * 64 + p * 8;
        f = 1024 + tid;       row = f >> 3; c = f & 7; p = c ^ (row & 7);
        bOff2 = ((row >> 5) * PAD_IMG + (row & 31)) * 512 + c * 8;
        lB2 = row * 64 + p * 8;
        f = 1536 + tid;       row = f >> 3; c = f & 7; p = c ^ (row & 7);
        bOff3 = ((row >> 5) * PAD_IMG + (row & 31)) * 512 + c * 8;
        lB3 = row * 64 + p * 8;
    }

    const size_t bImgBase = (size_t)b * PAD_IMG * PAD_IMG * 512;

    // prefetch state: 6 named uint4 scalars (SROA-safe)
    uint4 ra0, ra1, rb0, rb1, rb2, rb3;

    LOADSTEP(0);

    // fragment read addresses: this wave reads k-chunk q = kg*4+kch at
    // swizzled position q^(row&7); row&7 = rl&7 (wave bases %16==0).
    const int rl   = lane & 15;
    const int kch  = lane >> 4;                  // 0..3
    const int swz  = ((kg * 4 + kch) ^ (rl & 7)) * 8;
    const int arow = (wm * 64 + rl) * 64;
    const int brow = (wn * 128 + rl) * 64;

    for (int step = 0; step < 72; ++step) {
        unsigned short* Ab_lds = (step & 1) ? Alds1 : Alds0;
        unsigned short* Bb_lds = (step & 1) ? Blds1 : Blds0;
        COMMIT(Ab_lds, Bb_lds);  // vmcnt waits = loads issued last iter
        const int nxt = step + 1 < 72 ? step + 1 : 71;
        LOADSTEP(nxt);           // in flight across the raw barrier
        SYNC();

        // Incremental consumption: af0..3 + bfr[0] first (5 reads), then
        // per-ni: issue next bfr read, run 4 MFMAs on current bfr. Counted
        // lgkmcnt lets each MFMA group start as soon as ITS bfr landed;
        // later reads drain under MFMA -> LDS/MFMA overlap.
        bf16x8 af[4], bfr[8];
        #pragma unroll
        for (int mi = 0; mi < 4; ++mi)
            af[mi] = *(const bf16x8*)(Ab_lds + arow + mi * (16 * 64) + swz);
        bfr[0] = *(const bf16x8*)(Bb_lds + brow + 0 * (16 * 64) + swz);
        __builtin_amdgcn_s_setprio(1);
        #pragma unroll
        for (int ni = 0; ni < 8; ++ni) {
            if (ni < 7)
                bfr[ni + 1] =
                    *(const bf16x8*)(Bb_lds + brow + (ni + 1) * (16 * 64) + swz);
            #pragma unroll
            for (int mi = 0; mi < 4; ++mi)
                acc[mi][ni] = __builtin_amdgcn_mfma_f32_16x16x32_bf16(
                    af[mi], bfr[ni], acc[mi][ni], 0, 0, 0);
        }
        __builtin_amdgcn_s_setprio(0);
        // raw-SYNC safety: each wave drains its lgkm (reads+writes) before
        // the barrier; step+1 writes target the other buffer, whose readers
        // completed before barrier(step). Global loads legitimately cross.
    }

    // ---- epilogue: merge kg partials via LDS, scale, store ----
    // C frag layout: col(N)=lane&15, row(M)=(lane>>4)*4+reg [m89-verified]
    const int colp = lane & 15;
    const int rowq = (lane >> 4) * 4;
    float* ep = (float*)smem;                    // 96KB as f32
    float* reg = ep + wn * 8192;                 // 32KB region per wn
    for (int wmr = 0; wmr < 2; ++wmr) {
        __syncthreads();
        if (wm == wmr && kg == 1) {
            #pragma unroll
            for (int mi = 0; mi < 4; ++mi)
                #pragma unroll
                for (int ni = 0; ni < 8; ++ni)
                    *(f32x4*)(reg + ((mi * 8 + ni) * 64 + lane) * 4) =
                        acc[mi][ni];
        }
        __syncthreads();
        if (wm == wmr && kg == 0) {
            #pragma unroll
            for (int mi = 0; mi < 4; ++mi) {
                #pragma unroll
                for (int ni = 0; ni < 8; ++ni) {
                    const f32x4 o =
                        *(const f32x4*)(reg + ((mi * 8 + ni) * 64 + lane) * 4);
                    const int p = h0 * 32 + wn * 128 + ni * 16 + colp;
                    #pragma unroll
                    for (int r2 = 0; r2 < 4; ++r2) {
                        const int ol = wm * 64 + mi * 16 + rowq + r2;
                        out[(((size_t)b * 512 + m0 + ol) << 10) + p] =
                            (acc[mi][ni][r2] + o[r2]) * sclds[ol];
                    }
                }
            }
        }
    }
}

extern "C" void kernel_launch(void* const* d_in, const int* in_sizes, int n_in,
                              void* d_out, int out_size, void* d_ws, size_t ws_size,
                              hipStream_t stream) {
    const float* x     = (const float*)d_in[0];  // [16,512,32,32]
    const float* style = (const float*)d_in[1];  // [16,512]
    const float* aw    = (const float*)d_in[2];  // [512,512]
    const float* ab    = (const float*)d_in[3];  // [512]
    const float* cw    = (const float*)d_in[4];  // [512,512,3,3]
    float* out = (float*)d_out;

    char* ws = (char*)d_ws;
    float* s_buf          = (float*)(ws);                      //  32 KB
    float* scl            = (float*)(ws + 32768);              //  32 KB
    float* wsq            = (float*)(ws + 65536);              //   1 MB
    unsigned short* w_t   = (unsigned short*)(ws + 1114112);   // 4.5 MB bf16
    unsigned short* x_pad = (unsigned short*)(ws + 5832704);   // 18.9 MB bf16
    // total ws need: 24,772,608 B

    prep1<<<dim3(3072), 256, 0, stream>>>(cw, style, aw, ab, w_t, wsq, s_buf);
    prep2<<<dim3(6400), 256, 0, stream>>>(x, s_buf, wsq, x_pad, scl);
    conv_mfma<<<dim3(256), 512, 0, stream>>>(w_t, x_pad, scl, out);
}

// Round 12
// 171.238 us; speedup vs baseline: 1.0262x; 1.0009x over previous
//
#include <hip/hip_runtime.h>

// ModulatedConv2d: B=16, IN=512, OUT=512, STYLE=512, K=3, H=W=32
// out[b,o] = scale[b,o] * conv2d(x[b,i]*s[b,i], W[o,i])   (shared weights!)
// Conv = one implicit GEMM: M=512 out-ch, N=16384 (b,px), K=9x512.
// x staged as zero-padded NHWC bf16 -> no boundary masking.
//
// R12: 128x128 blk 4w 64x64 dbuf 2blk/CU: 91.6us. R16: 1 w/SIMD: 133us.
// R13/14: B-direct: ~161us (VMEM scatter). R15: raw lgkm barrier = R12.
// R17: 128x256 8w 2x2x2(kg) dbuf 1blk/CU: 86.5us. R18: 0.375@2blk: 90.3.
// R19: incremental-consumption source order: 85.0us NEUTRAL -- compiler
//      re-hoists LDS reads; source order doesn't survive. Serial model
//      (step = LDS-bytes + MFMA, 2833cy = 1242 + ~1600) confirmed 4x.
// R20 (this): two fronts.
//   conv: R19 + sched_group_barrier (T19) pinning {5 DS_READ} then
//      7x{1 DS_READ, 4 MFMA} + {4 MFMA} -- compile-time interleave the
//      compiler can't undo. Predict 62-72us/MfmaUtil 45-52% if ds/MFMA
//      pipes overlap; 84-87 if T19-null repeats.
//   prep (never touched in 12 rounds; gap constant 82-90us): G13 fixes --
//      float4 x loads (was scalar 4B, 67MB at half rate), float4 wl/aw/
//      style/wsq loads, paired w_t repack (uint stores, 512 blocks).
//      Predict (total-conv) 86 -> 72-80 if prep-bound; unchanged => floor.

#define BATCH   16
#define CIN     512
#define COUT    512
#define IMG     32
#define PAD_IMG 34

static constexpr float AFF_SCALE = 0.044194173824159216f;  // 1/sqrt(512)
static constexpr float W_SCALE   = 0.014731391274719739f;  // 1/sqrt(512*9)

typedef __bf16 bf16x8 __attribute__((ext_vector_type(8)));
typedef float  f32x4  __attribute__((ext_vector_type(4)));

__device__ inline unsigned short f2bf(float f) {
    union { float f; unsigned int u; } v; v.f = f;
    unsigned int u = v.u;
    unsigned int r = (u + 0x7FFFu + ((u >> 16) & 1u)) >> 16;
    return (unsigned short)r;
}

__device__ inline float waveReduceSum(float v) {
    #pragma unroll
    for (int off = 32; off > 0; off >>= 1) v += __shfl_xor(v, off, 64);
    return v;
}

// ---- kernel 1: fused prep ----
// blocks 0..511:    repack_w  (2 idx/thread: w_t uint stores, wsq float2)
// blocks 512..2559: compute_s (float4 loads)
__global__ void prep1(const float* __restrict__ cw,
                      const float* __restrict__ style,
                      const float* __restrict__ aw,
                      const float* __restrict__ ab,
                      unsigned short* __restrict__ w_t,
                      float* __restrict__ wsq,
                      float* __restrict__ s_out) {
    const int tid = threadIdx.x;
    if (blockIdx.x < 512) {
        __shared__ float wl[4608];                    // 512 idx x 9
        const float* src = cw + (size_t)blockIdx.x * 4608;
        for (int j = tid; j < 1152; j += 256)         // float4 loads
            *(float4*)(wl + j * 4) = *(const float4*)(src + j * 4);
        __syncthreads();
        const int idx0 = blockIdx.x * 512 + tid * 2;  // two consecutive idx
        const int base = tid * 18;
        float acc0 = 0.f, acc1 = 0.f;
        #pragma unroll
        for (int e = 0; e < 9; ++e) {
            float v0 = wl[base + e];
            float v1 = wl[base + 9 + e];
            acc0 += v0 * v0;
            acc1 += v1 * v1;
            unsigned int pk = (unsigned)f2bf(v0) | ((unsigned)f2bf(v1) << 16);
            *(unsigned int*)(w_t + (size_t)e * (COUT * CIN) + idx0) = pk;
        }
        *(float2*)(wsq + idx0) = make_float2(acc0, acc1);
    } else {
        const int q = blockIdx.x - 512;               // 0..2047
        const int b = q >> 7;
        const int i = (q & 127) * 4 + (tid >> 6);
        const int lane = tid & 63;
        const float4* a4 = (const float4*)(aw + (size_t)i * 512);
        const float4* s4 = (const float4*)(style + (size_t)b * 512);
        float sum = 0.f;
        #pragma unroll
        for (int r = 0; r < 2; ++r) {
            float4 av = a4[lane * 2 + r];
            float4 sv = s4[lane * 2 + r];
            sum += av.x * sv.x + av.y * sv.y + av.z * sv.z + av.w * sv.w;
        }
        sum = waveReduceSum(sum);
        if (lane == 0)
            s_out[b * 512 + i] = sum * AFF_SCALE + ab[i] + 1.0f;
    }
}

// ---- kernel 2: fused xpad + scale ----
__global__ void prep2(const float* __restrict__ x,
                      const float* __restrict__ s_in,
                      const float* __restrict__ wsq,
                      unsigned short* __restrict__ xpad,
                      float* __restrict__ scl) {
    const int tid = threadIdx.x;
    if (blockIdx.x >= 4352) {
        const int q = blockIdx.x - 4352;              // 0..2047
        const int b = q >> 7;                         // 0..15
        const int o = (q & 127) * 4 + (tid >> 6);     // 0..511
        const int lane = tid & 63;
        const float4* w4p = (const float4*)(wsq + (size_t)o * 512);
        const float4* s4p = (const float4*)(s_in + (size_t)b * 512);
        float sum = 0.f;
        #pragma unroll
        for (int r = 0; r < 2; ++r) {
            float4 wv = w4p[lane * 2 + r];
            float4 sv = s4p[lane * 2 + r];
            sum += sv.x * sv.x * wv.x + sv.y * sv.y * wv.y
                 + sv.z * sv.z * wv.z + sv.w * sv.w * wv.w;
        }
        sum = waveReduceSum(sum);
        if (lane == 0)
            scl[b * 512 + o] = W_SCALE * rsqrtf(W_SCALE * W_SCALE * sum + 1e-8f);
        return;
    }
    const int c0   = blockIdx.x & 7;                  // *64 channels
    const int rest = blockIdx.x >> 3;                 // 0..543
    const int hh   = rest % 34;
    const int b    = rest / 34;
    const int c0b  = c0 * 64;
    unsigned short* rowbase = xpad + (((size_t)b * PAD_IMG + hh) * PAD_IMG) * 512;

    if (hh == 0 || hh == PAD_IMG - 1) {
        for (int j = tid; j < 34 * 32; j += 256) {
            int ww = j >> 5, cp = (j & 31) * 2;
            *(unsigned int*)(rowbase + (size_t)ww * 512 + c0b + cp) = 0u;
        }
        return;
    }

    __shared__ float t[64][33];
    const int h = hh - 1;
    // float4 x loads: f = r*256+tid covers 64 ch x 8 w4-chunks; 8 lanes
    // per ch row -> 128B contiguous per group (G13 fix; was 8x scalar 4B).
    #pragma unroll
    for (int r = 0; r < 2; ++r) {
        const int f   = r * 256 + tid;                // 0..511
        const int chl = f >> 3;                       // 0..63
        const int w4  = (f & 7) * 4;
        float4 xv = *(const float4*)(
            x + (((size_t)b * 512 + c0b + chl) * IMG + h) * IMG + w4);
        const float sv = s_in[b * 512 + c0b + chl];
        t[chl][w4 + 0] = xv.x * sv;
        t[chl][w4 + 1] = xv.y * sv;
        t[chl][w4 + 2] = xv.z * sv;
        t[chl][w4 + 3] = xv.w * sv;
    }
    __syncthreads();
    {
        const int p  = tid >> 3;
        const int cc = (tid & 7) * 8;
        unsigned short* dst = rowbase + (size_t)(p + 1) * 512 + c0b + cc;
        uint4 pk;
        pk.x = (unsigned)f2bf(t[cc + 0][p]) | ((unsigned)f2bf(t[cc + 1][p]) << 16);
        pk.y = (unsigned)f2bf(t[cc + 2][p]) | ((unsigned)f2bf(t[cc + 3][p]) << 16);
        pk.z = (unsigned)f2bf(t[cc + 4][p]) | ((unsigned)f2bf(t[cc + 5][p]) << 16);
        pk.w = (unsigned)f2bf(t[cc + 6][p]) | ((unsigned)f2bf(t[cc + 7][p]) << 16);
        *(uint4*)dst = pk;
    }
    if (tid < 64) {
        int ww = (tid >> 5) ? (PAD_IMG - 1) : 0;
        int cp = (tid & 31) * 2;
        *(unsigned int*)(rowbase + (size_t)ww * 512 + c0b + cp) = 0u;
    }
}

// ---- kernel 3: implicit-GEMM conv, 128x256 block, 8 waves, BK=64 ----
// Waves: wm=(wid>>1)&1, wn=wid&1, kg=wid>>2. Wave tile 64x128 x k-half.
// Reg-staged dbuf LDS, raw lgkm barrier, XOR swizzle, grid 256 XCD-swz.
// R20: sched_group_barrier pins {5 DS_READ} + 7x{1 DS_READ,4 MFMA} +
// {4 MFMA} so the read-burst can't be hoisted ahead of the MFMAs.

#define SYNC() do {                                                           \
    asm volatile("s_waitcnt lgkmcnt(0)" ::: "memory");                        \
    __builtin_amdgcn_s_barrier();                                             \
    __builtin_amdgcn_sched_barrier(0);                                        \
} while (0)

#define LOADSTEP(stp) do {                                                    \
    const int e_  = (stp) >> 3;                                               \
    const int kc_ = ((stp) & 7) << 6;                                         \
    const int kh_ = (e_ * 11) >> 5;                                           \
    const int kw_ = e_ - kh_ * 3;                                             \
    const unsigned short* Ab_ = wt + (size_t)e_ * (COUT * CIN)                \
                                   + (size_t)m0 * 512 + kc_;                  \
    const unsigned short* Bb_ = xpad + bImgBase                               \
                              + (size_t)((h0 + kh_) * PAD_IMG + kw_) * 512    \
                              + kc_;                                          \
    ra0 = *(const uint4*)(Ab_ + aOff0);                                       \
    ra1 = *(const uint4*)(Ab_ + aOff1);                                       \
    rb0 = *(const uint4*)(Bb_ + bOff0);                                       \
    rb1 = *(const uint4*)(Bb_ + bOff1);                                       \
    rb2 = *(const uint4*)(Bb_ + bOff2);                                       \
    rb3 = *(const uint4*)(Bb_ + bOff3);                                       \
} while (0)

#define COMMIT(Albuf, Blbuf) do {                                             \
    *(uint4*)((Albuf) + lA0) = ra0;                                           \
    *(uint4*)((Albuf) + lA1) = ra1;                                           \
    *(uint4*)((Blbuf) + lB0) = rb0;                                           \
    *(uint4*)((Blbuf) + lB1) = rb1;                                           \
    *(uint4*)((Blbuf) + lB2) = rb2;                                           \
    *(uint4*)((Blbuf) + lB3) = rb3;                                           \
} while (0)

__global__ __launch_bounds__(512, 2) void conv_mfma(
    const unsigned short* __restrict__ wt,    // [9][512][512] bf16
    const unsigned short* __restrict__ xpad,  // [16][34][34][512] bf16
    const float* __restrict__ scl,            // [16][512]
    float* __restrict__ out)                  // [16][512][32][32]
{
    // 96KB carved: A dbuf 2x16KB, B dbuf 2x32KB; epilogue reuses as f32.
    __shared__ __align__(16) unsigned char smem[98304];
    unsigned short* Alds0 = (unsigned short*)(smem);
    unsigned short* Alds1 = (unsigned short*)(smem + 16384);
    unsigned short* Blds0 = (unsigned short*)(smem + 32768);
    unsigned short* Blds1 = (unsigned short*)(smem + 65536);
    __shared__ float sclds[128];

    const int tid = threadIdx.x;
    // XCD swizzle: 256 blocks, id&7 -> XCD. Per XCD: 8 N-blocks x 4 m.
    const int id    = blockIdx.x;
    const int xcd   = id & 7;
    const int local = id >> 3;                   // 0..31
    const int gp    = xcd * 8 + (local >> 2);    // 0..63  N-block (b, hg)
    const int m0  = (local & 3) * 128;
    const int b   = gp >> 2;                     // 0..15
    const int h0  = (gp & 3) * 8;                // 0,8,16,24

    if (tid < 128) sclds[tid] = scl[b * 512 + m0 + tid];

    const int wid  = tid >> 6;
    const int lane = tid & 63;
    const int wm = (wid >> 1) & 1;               // M half (64 rows)
    const int wn = wid & 1;                      // N half (128 px)
    const int kg = wid >> 2;                     // k-group (k-half of step)

    const f32x4 vzero = {0.f, 0.f, 0.f, 0.f};
    f32x4 acc[4][8];
    #pragma unroll
    for (int i = 0; i < 4; ++i)
        #pragma unroll
        for (int j = 0; j < 8; ++j) acc[i][j] = vzero;

    // staging offsets (named scalars -- R9 SROA lesson). 512 threads:
    // A: f = r*512+tid, r=0..1 -> rows 0..127, chunk c=f&7.
    // B: f = r*512+tid, r=0..3 -> rows 0..255 (px index in N-tile).
    // XOR swizzle p = c ^ (row&7).
    int aOff0, aOff1, lA0, lA1;
    int bOff0, bOff1, bOff2, bOff3, lB0, lB1, lB2, lB3;
    {
        int f, row, c, p;
        f = tid;              row = f >> 3; c = f & 7; p = c ^ (row & 7);
        aOff0 = row * 512 + c * 8;  lA0 = row * 64 + p * 8;
        f = 512 + tid;        row = f >> 3; c = f & 7; p = c ^ (row & 7);
        aOff1 = row * 512 + c * 8;  lA1 = row * 64 + p * 8;

        f = tid;              row = f >> 3; c = f & 7; p = c ^ (row & 7);
        bOff0 = ((row >> 5) * PAD_IMG + (row & 31)) * 512 + c * 8;
        lB0 = row * 64 + p * 8;
        f = 512 + tid;        row = f >> 3; c = f & 7; p = c ^ (row & 7);
        bOff1 = ((row >> 5) * PAD_IMG + (row & 31)) * 512 + c * 8;
        lB1 = row * 64 + p * 8;
        f = 1024 + tid;       row = f >> 3; c = f & 7; p = c ^ (row & 7);
        bOff2 = ((row >> 5) * PAD_IMG + (row & 31)) * 512 + c * 8;
        lB2 = row * 64 + p * 8;
        f = 1536 + tid;       row = f >> 3; c = f & 7; p = c ^ (row & 7);
        bOff3 = ((row >> 5) * PAD_IMG + (row & 31)) * 512 + c * 8;
        lB3 = row * 64 + p * 8;
    }

    const size_t bImgBase = (size_t)b * PAD_IMG * PAD_IMG * 512;

    // prefetch state: 6 named uint4 scalars (SROA-safe)
    uint4 ra0, ra1, rb0, rb1, rb2, rb3;

    LOADSTEP(0);

    // fragment read addresses: this wave reads k-chunk q = kg*4+kch at
    // swizzled position q^(row&7); row&7 = rl&7 (wave bases %16==0).
    const int rl   = lane & 15;
    const int kch  = lane >> 4;                  // 0..3
    const int swz  = ((kg * 4 + kch) ^ (rl & 7)) * 8;
    const int arow = (wm * 64 + rl) * 64;
    const int brow = (wn * 128 + rl) * 64;

    for (int step = 0; step < 72; ++step) {
        unsigned short* Ab_lds = (step & 1) ? Alds1 : Alds0;
        unsigned short* Bb_lds = (step & 1) ? Blds1 : Blds0;
        COMMIT(Ab_lds, Bb_lds);  // vmcnt waits = loads issued last iter
        const int nxt = step + 1 < 72 ? step + 1 : 71;
        LOADSTEP(nxt);           // in flight across the raw barrier
        SYNC();

        // T19 sched_group_barrier pins the interleave: {5 DS_READ} then
        // 7x{1 DS_READ, 4 MFMA} + {4 MFMA}. Each MFMA group starts once
        // ITS bfr landed (compiler-counted lgkmcnt); later reads drain
        // under MFMA -> LDS/MFMA pipe overlap.
        bf16x8 af[4], bfr[8];
        #pragma unroll
        for (int mi = 0; mi < 4; ++mi)
            af[mi] = *(const bf16x8*)(Ab_lds + arow + mi * (16 * 64) + swz);
        bfr[0] = *(const bf16x8*)(Bb_lds + brow + 0 * (16 * 64) + swz);
        __builtin_amdgcn_sched_group_barrier(0x100, 5, 0);  // 5 DS_READ
        __builtin_amdgcn_s_setprio(1);
        #pragma unroll
        for (int ni = 0; ni < 8; ++ni) {
            if (ni < 7)
                bfr[ni + 1] =
                    *(const bf16x8*)(Bb_lds + brow + (ni + 1) * (16 * 64) + swz);
            #pragma unroll
            for (int mi = 0; mi < 4; ++mi)
                acc[mi][ni] = __builtin_amdgcn_mfma_f32_16x16x32_bf16(
                    af[mi], bfr[ni], acc[mi][ni], 0, 0, 0);
            if (ni < 7)
                __builtin_amdgcn_sched_group_barrier(0x100, 1, 0);  // 1 DS_READ
            __builtin_amdgcn_sched_group_barrier(0x008, 4, 0);      // 4 MFMA
        }
        __builtin_amdgcn_s_setprio(0);
        // raw-SYNC safety: each wave drains its lgkm (reads+writes) before
        // the barrier; step+1 writes target the other buffer, whose readers
        // completed before barrier(step). Global loads legitimately cross.
    }

    // ---- epilogue: merge kg partials via LDS, scale, store ----
    // C frag layout: col(N)=lane&15, row(M)=(lane>>4)*4+reg [m89-verified]
    const int colp = lane & 15;
    const int rowq = (lane >> 4) * 4;
    float* ep = (float*)smem;                    // 96KB as f32
    float* reg = ep + wn * 8192;                 // 32KB region per wn
    for (int wmr = 0; wmr < 2; ++wmr) {
        __syncthreads();
        if (wm == wmr && kg == 1) {
            #pragma unroll
            for (int mi = 0; mi < 4; ++mi)
                #pragma unroll
                for (int ni = 0; ni < 8; ++ni)
                    *(f32x4*)(reg + ((mi * 8 + ni) * 64 + lane) * 4) =
                        acc[mi][ni];
        }
        __syncthreads();
        if (wm == wmr && kg == 0) {
            #pragma unroll
            for (int mi = 0; mi < 4; ++mi) {
                #pragma unroll
                for (int ni = 0; ni < 8; ++ni) {
                    const f32x4 o =
                        *(const f32x4*)(reg + ((mi * 8 + ni) * 64 + lane) * 4);
                    const int p = h0 * 32 + wn * 128 + ni * 16 + colp;
                    #pragma unroll
                    for (int r2 = 0; r2 < 4; ++r2) {
                        const int ol = wm * 64 + mi * 16 + rowq + r2;
                        out[(((size_t)b * 512 + m0 + ol) << 10) + p] =
                            (acc[mi][ni][r2] + o[r2]) * sclds[ol];
                    }
                }
            }
        }
    }
}

extern "C" void kernel_launch(void* const* d_in, const int* in_sizes, int n_in,
                              void* d_out, int out_size, void* d_ws, size_t ws_size,
                              hipStream_t stream) {
    const float* x     = (const float*)d_in[0];  // [16,512,32,32]
    const float* style = (const float*)d_in[1];  // [16,512]
    const float* aw    = (const float*)d_in[2];  // [512,512]
    const float* ab    = (const float*)d_in[3];  // [512]
    const float* cw    = (const float*)d_in[4];  // [512,512,3,3]
    float* out = (float*)d_out;

    char* ws = (char*)d_ws;
    float* s_buf          = (float*)(ws);                      //  32 KB
    float* scl            = (float*)(ws + 32768);              //  32 KB
    float* wsq            = (float*)(ws + 65536);              //   1 MB
    unsigned short* w_t   = (unsigned short*)(ws + 1114112);   // 4.5 MB bf16
    unsigned short* x_pad = (unsigned short*)(ws + 5832704);   // 18.9 MB bf16
    // total ws need: 24,772,608 B

    prep1<<<dim3(2560), 256, 0, stream>>>(cw, style, aw, ab, w_t, wsq, s_buf);
    prep2<<<dim3(6400), 256, 0, stream>>>(x, s_buf, wsq, x_pad, scl);
    conv_mfma<<<dim3(256), 512, 0, stream>>>(w_t, x_pad, scl, out);
}

// Round 13
// 170.959 us; speedup vs baseline: 1.0279x; 1.0016x over previous
//
#include <hip/hip_runtime.h>

// ModulatedConv2d: B=16, IN=512, OUT=512, STYLE=512, K=3, H=W=32
// out[b,o] = scale[b,o] * conv2d(x[b,i]*s[b,i], W[o,i])   (shared weights!)
// Conv = one implicit GEMM: M=512 out-ch, N=16384 (b,px), K=9x512.
// x staged as zero-padded NHWC bf16 -> no boundary masking.
//
// R12: 128x128 4w dbuf 2blk/CU: 91.6us. R16: 1w/SIMD: 133us. R18: 90.3us.
// R13/14: B-direct: ~161us. R15: raw lgkm barrier = R12 (drain not cost).
// R17: 128x256 8w 2(wm)x2(wn)x2(kg) dbuf 1blk/CU: 86.5us.
// R19: incremental-consumption SOURCE order: 85.0 (compiler re-hoists).
// R20: + sched_group_barrier pinning the 12 reads under MFMA: 81.8us,
//      MfmaUtil 39.3% -- T19 real here (+4%). Prep vectorization: no
//      visible total change (non-conv ~89us = launch/harness floor).
// R21 (this): writes under MFMA too. COMMIT's 6 ds_writes moved INTO the
//      MFMA phase (they target buf^1, barrier-safe: its readers finished
//      before the PREVIOUS barrier). One barrier per step. E/O staging
//      reg sets, 2x-unrolled loop (static indices, R9/R14 SROA lesson).
//      Pin: {5 DS_READ} + 7x{1 DS_READ,1 DS_WRITE,4 MFMA}-ish + VMEM mid.
//      Step -> 5-read ramp + max(MFMA 1242, LDS 1728) + barrier ~1900cy.
//      Predict: conv 62-72us, MfmaUtil 46-52%, VGPR ~128 (+128 AGPR = at
//      cap; WRITE>>33MB = spill tripwire). Neutral 79-83 => structural
//      floor of this family.

#define BATCH   16
#define CIN     512
#define COUT    512
#define IMG     32
#define PAD_IMG 34

static constexpr float AFF_SCALE = 0.044194173824159216f;  // 1/sqrt(512)
static constexpr float W_SCALE   = 0.014731391274719739f;  // 1/sqrt(512*9)

typedef __bf16 bf16x8 __attribute__((ext_vector_type(8)));
typedef float  f32x4  __attribute__((ext_vector_type(4)));

__device__ inline unsigned short f2bf(float f) {
    union { float f; unsigned int u; } v; v.f = f;
    unsigned int u = v.u;
    unsigned int r = (u + 0x7FFFu + ((u >> 16) & 1u)) >> 16;
    return (unsigned short)r;
}

__device__ inline float waveReduceSum(float v) {
    #pragma unroll
    for (int off = 32; off > 0; off >>= 1) v += __shfl_xor(v, off, 64);
    return v;
}

// ---- kernel 1: fused prep ----
__global__ void prep1(const float* __restrict__ cw,
                      const float* __restrict__ style,
                      const float* __restrict__ aw,
                      const float* __restrict__ ab,
                      unsigned short* __restrict__ w_t,
                      float* __restrict__ wsq,
                      float* __restrict__ s_out) {
    const int tid = threadIdx.x;
    if (blockIdx.x < 512) {
        __shared__ float wl[4608];                    // 512 idx x 9
        const float* src = cw + (size_t)blockIdx.x * 4608;
        for (int j = tid; j < 1152; j += 256)         // float4 loads
            *(float4*)(wl + j * 4) = *(const float4*)(src + j * 4);
        __syncthreads();
        const int idx0 = blockIdx.x * 512 + tid * 2;  // two consecutive idx
        const int base = tid * 18;
        float acc0 = 0.f, acc1 = 0.f;
        #pragma unroll
        for (int e = 0; e < 9; ++e) {
            float v0 = wl[base + e];
            float v1 = wl[base + 9 + e];
            acc0 += v0 * v0;
            acc1 += v1 * v1;
            unsigned int pk = (unsigned)f2bf(v0) | ((unsigned)f2bf(v1) << 16);
            *(unsigned int*)(w_t + (size_t)e * (COUT * CIN) + idx0) = pk;
        }
        *(float2*)(wsq + idx0) = make_float2(acc0, acc1);
    } else {
        const int q = blockIdx.x - 512;               // 0..2047
        const int b = q >> 7;
        const int i = (q & 127) * 4 + (tid >> 6);
        const int lane = tid & 63;
        const float4* a4 = (const float4*)(aw + (size_t)i * 512);
        const float4* s4 = (const float4*)(style + (size_t)b * 512);
        float sum = 0.f;
        #pragma unroll
        for (int r = 0; r < 2; ++r) {
            float4 av = a4[lane * 2 + r];
            float4 sv = s4[lane * 2 + r];
            sum += av.x * sv.x + av.y * sv.y + av.z * sv.z + av.w * sv.w;
        }
        sum = waveReduceSum(sum);
        if (lane == 0)
            s_out[b * 512 + i] = sum * AFF_SCALE + ab[i] + 1.0f;
    }
}

// ---- kernel 2: fused xpad + scale ----
__global__ void prep2(const float* __restrict__ x,
                      const float* __restrict__ s_in,
                      const float* __restrict__ wsq,
                      unsigned short* __restrict__ xpad,
                      float* __restrict__ scl) {
    const int tid = threadIdx.x;
    if (blockIdx.x >= 4352) {
        const int q = blockIdx.x - 4352;              // 0..2047
        const int b = q >> 7;                         // 0..15
        const int o = (q & 127) * 4 + (tid >> 6);     // 0..511
        const int lane = tid & 63;
        const float4* w4p = (const float4*)(wsq + (size_t)o * 512);
        const float4* s4p = (const float4*)(s_in + (size_t)b * 512);
        float sum = 0.f;
        #pragma unroll
        for (int r = 0; r < 2; ++r) {
            float4 wv = w4p[lane * 2 + r];
            float4 sv = s4p[lane * 2 + r];
            sum += sv.x * sv.x * wv.x + sv.y * sv.y * wv.y
                 + sv.z * sv.z * wv.z + sv.w * sv.w * wv.w;
        }
        sum = waveReduceSum(sum);
        if (lane == 0)
            scl[b * 512 + o] = W_SCALE * rsqrtf(W_SCALE * W_SCALE * sum + 1e-8f);
        return;
    }
    const int c0   = blockIdx.x & 7;                  // *64 channels
    const int rest = blockIdx.x >> 3;                 // 0..543
    const int hh   = rest % 34;
    const int b    = rest / 34;
    const int c0b  = c0 * 64;
    unsigned short* rowbase = xpad + (((size_t)b * PAD_IMG + hh) * PAD_IMG) * 512;

    if (hh == 0 || hh == PAD_IMG - 1) {
        for (int j = tid; j < 34 * 32; j += 256) {
            int ww = j >> 5, cp = (j & 31) * 2;
            *(unsigned int*)(rowbase + (size_t)ww * 512 + c0b + cp) = 0u;
        }
        return;
    }

    __shared__ float t[64][33];
    const int h = hh - 1;
    #pragma unroll
    for (int r = 0; r < 2; ++r) {
        const int f   = r * 256 + tid;                // 0..511
        const int chl = f >> 3;                       // 0..63
        const int w4  = (f & 7) * 4;
        float4 xv = *(const float4*)(
            x + (((size_t)b * 512 + c0b + chl) * IMG + h) * IMG + w4);
        const float sv = s_in[b * 512 + c0b + chl];
        t[chl][w4 + 0] = xv.x * sv;
        t[chl][w4 + 1] = xv.y * sv;
        t[chl][w4 + 2] = xv.z * sv;
        t[chl][w4 + 3] = xv.w * sv;
    }
    __syncthreads();
    {
        const int p  = tid >> 3;
        const int cc = (tid & 7) * 8;
        unsigned short* dst = rowbase + (size_t)(p + 1) * 512 + c0b + cc;
        uint4 pk;
        pk.x = (unsigned)f2bf(t[cc + 0][p]) | ((unsigned)f2bf(t[cc + 1][p]) << 16);
        pk.y = (unsigned)f2bf(t[cc + 2][p]) | ((unsigned)f2bf(t[cc + 3][p]) << 16);
        pk.z = (unsigned)f2bf(t[cc + 4][p]) | ((unsigned)f2bf(t[cc + 5][p]) << 16);
        pk.w = (unsigned)f2bf(t[cc + 6][p]) | ((unsigned)f2bf(t[cc + 7][p]) << 16);
        *(uint4*)dst = pk;
    }
    if (tid < 64) {
        int ww = (tid >> 5) ? (PAD_IMG - 1) : 0;
        int cp = (tid & 31) * 2;
        *(unsigned int*)(rowbase + (size_t)ww * 512 + c0b + cp) = 0u;
    }
}

// ---- kernel 3: implicit-GEMM conv, 128x256 block, 8 waves, BK=64 ----
// Waves: wm=(wid>>1)&1, wn=wid&1, kg=wid>>2. Wave tile 64x128 x k-half.
// R21 phase: reads AND commit-writes pinned under MFMA via SGB; one raw
// barrier per step. E/O staging reg sets, 2x-unrolled loop.

#define SYNC() do {                                                           \
    asm volatile("s_waitcnt lgkmcnt(0)" ::: "memory");                        \
    __builtin_amdgcn_s_barrier();                                             \
    __builtin_amdgcn_sched_barrier(0);                                        \
} while (0)

// loader into reg set S (A or B): 2 A-slabs + 4 B-slabs
#define LOADSTEP(stp, S) do {                                                 \
    const int e_  = (stp) >> 3;                                               \
    const int kc_ = ((stp) & 7) << 6;                                         \
    const int kh_ = (e_ * 11) >> 5;                                           \
    const int kw_ = e_ - kh_ * 3;                                             \
    const unsigned short* Ab_ = wt + (size_t)e_ * (COUT * CIN)                \
                                   + (size_t)m0 * 512 + kc_;                  \
    const unsigned short* Bb_ = xpad + bImgBase                               \
                              + (size_t)((h0 + kh_) * PAD_IMG + kw_) * 512    \
                              + kc_;                                          \
    ra0##S = *(const uint4*)(Ab_ + aOff0);                                    \
    ra1##S = *(const uint4*)(Ab_ + aOff1);                                    \
    rb0##S = *(const uint4*)(Bb_ + bOff0);                                    \
    rb1##S = *(const uint4*)(Bb_ + bOff1);                                    \
    rb2##S = *(const uint4*)(Bb_ + bOff2);                                    \
    rb3##S = *(const uint4*)(Bb_ + bOff3);                                    \
} while (0)

#define MFMA4(ni, bc)                                                         \
    acc[0][ni] = __builtin_amdgcn_mfma_f32_16x16x32_bf16(af0, bc, acc[0][ni], 0, 0, 0); \
    acc[1][ni] = __builtin_amdgcn_mfma_f32_16x16x32_bf16(af1, bc, acc[1][ni], 0, 0, 0); \
    acc[2][ni] = __builtin_amdgcn_mfma_f32_16x16x32_bf16(af2, bc, acc[2][ni], 0, 0, 0); \
    acc[3][ni] = __builtin_amdgcn_mfma_f32_16x16x32_bf16(af3, bc, acc[3][ni], 0, 0, 0)

#define PIN_R() __builtin_amdgcn_sched_group_barrier(0x100, 1, 0)
#define PIN_W() __builtin_amdgcn_sched_group_barrier(0x200, 1, 0)
#define PIN_M() __builtin_amdgcn_sched_group_barrier(0x008, 4, 0)
#define PIN_V() __builtin_amdgcn_sched_group_barrier(0x020, 3, 0)

// One step: read ARD/BRD, commit reg set CS -> AWR/BWR under MFMA, issue
// next loads into set LS. Ends WITHOUT barrier (caller does SYNC).
#define PHASE(ARD, BRD, AWR, BWR, CS, LS, nxt) do {                           \
    bf16x8 af0, af1, af2, af3, bf0, bf1, bf2, bf3, bf4, bf5, bf6, bf7;        \
    af0 = *(const bf16x8*)((ARD) + arow + 0 * 1024 + swz);                    \
    af1 = *(const bf16x8*)((ARD) + arow + 1 * 1024 + swz);                    \
    af2 = *(const bf16x8*)((ARD) + arow + 2 * 1024 + swz);                    \
    af3 = *(const bf16x8*)((ARD) + arow + 3 * 1024 + swz);                    \
    bf0 = *(const bf16x8*)((BRD) + brow + 0 * 1024 + swz);                    \
    __builtin_amdgcn_sched_group_barrier(0x100, 5, 0);                        \
    LOADSTEP(nxt, LS);                                                        \
    __builtin_amdgcn_s_setprio(1);                                            \
    bf1 = *(const bf16x8*)((BRD) + brow + 1 * 1024 + swz);                    \
    *(uint4*)((AWR) + lA0) = ra0##CS;                                         \
    MFMA4(0, bf0); PIN_R(); PIN_W(); PIN_M();                                 \
    bf2 = *(const bf16x8*)((BRD) + brow + 2 * 1024 + swz);                    \
    *(uint4*)((AWR) + lA1) = ra1##CS;                                         \
    MFMA4(1, bf1); PIN_R(); PIN_W(); PIN_M();                                 \
    bf3 = *(const bf16x8*)((BRD) + brow + 3 * 1024 + swz);                    \
    *(uint4*)((BWR) + lB0) = rb0##CS;                                         \
    MFMA4(2, bf2); PIN_R(); PIN_W(); PIN_M(); PIN_V();                        \
    bf4 = *(const bf16x8*)((BRD) + brow + 4 * 1024 + swz);                    \
    *(uint4*)((BWR) + lB1) = rb1##CS;                                         \
    MFMA4(3, bf3); PIN_R(); PIN_W(); PIN_M();                                 \
    bf5 = *(const bf16x8*)((BRD) + brow + 5 * 1024 + swz);                    \
    *(uint4*)((BWR) + lB2) = rb2##CS;                                         \
    MFMA4(4, bf4); PIN_R(); PIN_W(); PIN_M(); PIN_V();                        \
    bf6 = *(const bf16x8*)((BRD) + brow + 6 * 1024 + swz);                    \
    *(uint4*)((BWR) + lB3) = rb3##CS;                                         \
    MFMA4(5, bf5); PIN_R(); PIN_W(); PIN_M();                                 \
    bf7 = *(const bf16x8*)((BRD) + brow + 7 * 1024 + swz);                    \
    MFMA4(6, bf6); PIN_R(); PIN_M();                                          \
    MFMA4(7, bf7); PIN_M();                                                   \
    __builtin_amdgcn_s_setprio(0);                                            \
} while (0)

__global__ __launch_bounds__(512, 2) void conv_mfma(
    const unsigned short* __restrict__ wt,    // [9][512][512] bf16
    const unsigned short* __restrict__ xpad,  // [16][34][34][512] bf16
    const float* __restrict__ scl,            // [16][512]
    float* __restrict__ out)                  // [16][512][32][32]
{
    // 96KB carved: A dbuf 2x16KB, B dbuf 2x32KB; epilogue reuses as f32.
    __shared__ __align__(16) unsigned char smem[98304];
    unsigned short* Alds0 = (unsigned short*)(smem);
    unsigned short* Alds1 = (unsigned short*)(smem + 16384);
    unsigned short* Blds0 = (unsigned short*)(smem + 32768);
    unsigned short* Blds1 = (unsigned short*)(smem + 65536);
    __shared__ float sclds[128];

    const int tid = threadIdx.x;
    // XCD swizzle: 256 blocks, id&7 -> XCD. Per XCD: 8 N-blocks x 4 m.
    const int id    = blockIdx.x;
    const int xcd   = id & 7;
    const int local = id >> 3;                   // 0..31
    const int gp    = xcd * 8 + (local >> 2);    // 0..63  N-block (b, hg)
    const int m0  = (local & 3) * 128;
    const int b   = gp >> 2;                     // 0..15
    const int h0  = (gp & 3) * 8;                // 0,8,16,24

    if (tid < 128) sclds[tid] = scl[b * 512 + m0 + tid];

    const int wid  = tid >> 6;
    const int lane = tid & 63;
    const int wm = (wid >> 1) & 1;               // M half (64 rows)
    const int wn = wid & 1;                      // N half (128 px)
    const int kg = wid >> 2;                     // k-group (k-half of step)

    const f32x4 vzero = {0.f, 0.f, 0.f, 0.f};
    f32x4 acc[4][8];
    #pragma unroll
    for (int i = 0; i < 4; ++i)
        #pragma unroll
        for (int j = 0; j < 8; ++j) acc[i][j] = vzero;

    // staging offsets (named scalars -- R9 SROA lesson). 512 threads:
    // A: f = r*512+tid, r=0..1 -> rows 0..127. B: r=0..3 -> px 0..255.
    // XOR swizzle p = c ^ (row&7).
    int aOff0, aOff1, lA0, lA1;
    int bOff0, bOff1, bOff2, bOff3, lB0, lB1, lB2, lB3;
    {
        int f, row, c, p;
        f = tid;              row = f >> 3; c = f & 7; p = c ^ (row & 7);
        aOff0 = row * 512 + c * 8;  lA0 = row * 64 + p * 8;
        f = 512 + tid;        row = f >> 3; c = f & 7; p = c ^ (row & 7);
        aOff1 = row * 512 + c * 8;  lA1 = row * 64 + p * 8;

        f = tid;              row = f >> 3; c = f & 7; p = c ^ (row & 7);
        bOff0 = ((row >> 5) * PAD_IMG + (row & 31)) * 512 + c * 8;
        lB0 = row * 64 + p * 8;
        f = 512 + tid;        row = f >> 3; c = f & 7; p = c ^ (row & 7);
        bOff1 = ((row >> 5) * PAD_IMG + (row & 31)) * 512 + c * 8;
        lB1 = row * 64 + p * 8;
        f = 1024 + tid;       row = f >> 3; c = f & 7; p = c ^ (row & 7);
        bOff2 = ((row >> 5) * PAD_IMG + (row & 31)) * 512 + c * 8;
        lB2 = row * 64 + p * 8;
        f = 1536 + tid;       row = f >> 3; c = f & 7; p = c ^ (row & 7);
        bOff3 = ((row >> 5) * PAD_IMG + (row & 31)) * 512 + c * 8;
        lB3 = row * 64 + p * 8;
    }

    const size_t bImgBase = (size_t)b * PAD_IMG * PAD_IMG * 512;

    // E/O prefetch reg sets: 12 named uint4 scalars (SROA-safe)
    uint4 ra0A, ra1A, rb0A, rb1A, rb2A, rb3A;
    uint4 ra0B, ra1B, rb0B, rb1B, rb2B, rb3B;

    // fragment read addresses: wave reads k-chunk q = kg*4+kch at
    // swizzled position q^(row&7); row&7 = rl&7 (wave bases %16==0).
    const int rl   = lane & 15;
    const int kch  = lane >> 4;                  // 0..3
    const int swz  = ((kg * 4 + kch) ^ (rl & 7)) * 8;
    const int arow = (wm * 64 + rl) * 64;
    const int brow = (wn * 128 + rl) * 64;

    // prologue: step0 -> buf0; step1 loads in flight (set B)
    LOADSTEP(0, A);
    *(uint4*)(Alds0 + lA0) = ra0A;
    *(uint4*)(Alds0 + lA1) = ra1A;
    *(uint4*)(Blds0 + lB0) = rb0A;
    *(uint4*)(Blds0 + lB1) = rb1A;
    *(uint4*)(Blds0 + lB2) = rb2A;
    *(uint4*)(Blds0 + lB3) = rb3A;
    LOADSTEP(1, B);
    SYNC();

    // 72 steps as 36 double-iterations; all indices static.
    for (int t = 0; t < 36; ++t) {
        const int s = 2 * t;
        const int n2 = (s + 2 < 72) ? s + 2 : 71;
        const int n3 = (s + 3 < 72) ? s + 3 : 71;
        // even: read buf0 (step s); commit set B (step s+1) -> buf1;
        //       load step s+2 -> set A
        PHASE(Alds0, Blds0, Alds1, Blds1, B, A, n2);
        SYNC();
        // odd: read buf1 (step s+1); commit set A (step s+2) -> buf0;
        //      load step s+3 -> set B
        PHASE(Alds1, Blds1, Alds0, Blds0, A, B, n3);
        SYNC();
        // barrier-safety: writes to a buffer occur one full phase after
        // its last readers drained (lgkmcnt(0) before that phase's SYNC).
    }

    // ---- epilogue: merge kg partials via LDS, scale, store ----
    // C frag layout: col(N)=lane&15, row(M)=(lane>>4)*4+reg [m89-verified]
    const int colp = lane & 15;
    const int rowq = (lane >> 4) * 4;
    float* ep = (float*)smem;                    // 96KB as f32
    float* reg = ep + wn * 8192;                 // 32KB region per wn
    for (int wmr = 0; wmr < 2; ++wmr) {
        __syncthreads();
        if (wm == wmr && kg == 1) {
            #pragma unroll
            for (int mi = 0; mi < 4; ++mi)
                #pragma unroll
                for (int ni = 0; ni < 8; ++ni)
                    *(f32x4*)(reg + ((mi * 8 + ni) * 64 + lane) * 4) =
                        acc[mi][ni];
        }
        __syncthreads();
        if (wm == wmr && kg == 0) {
            #pragma unroll
            for (int mi = 0; mi < 4; ++mi) {
                #pragma unroll
                for (int ni = 0; ni < 8; ++ni) {
                    const f32x4 o =
                        *(const f32x4*)(reg + ((mi * 8 + ni) * 64 + lane) * 4);
                    const int p = h0 * 32 + wn * 128 + ni * 16 + colp;
                    #pragma unroll
                    for (int r2 = 0; r2 < 4; ++r2) {
                        const int ol = wm * 64 + mi * 16 + rowq + r2;
                        out[(((size_t)b * 512 + m0 + ol) << 10) + p] =
                            (acc[mi][ni][r2] + o[r2]) * sclds[ol];
                    }
                }
            }
        }
    }
}

extern "C" void kernel_launch(void* const* d_in, const int* in_sizes, int n_in,
                              void* d_out, int out_size, void* d_ws, size_t ws_size,
                              hipStream_t stream) {
    const float* x     = (const float*)d_in[0];  // [16,512,32,32]
    const float* style = (const float*)d_in[1];  // [16,512]
    const float* aw    = (const float*)d_in[2];  // [512,512]
    const float* ab    = (const float*)d_in[3];  // [512]
    const float* cw    = (const float*)d_in[4];  // [512,512,3,3]
    float* out = (float*)d_out;

    char* ws = (char*)d_ws;
    float* s_buf          = (float*)(ws);                      //  32 KB
    float* scl            = (float*)(ws + 32768);              //  32 KB
    float* wsq            = (float*)(ws + 65536);              //   1 MB
    unsigned short* w_t   = (unsigned short*)(ws + 1114112);   // 4.5 MB bf16
    unsigned short* x_pad = (unsigned short*)(ws + 5832704);   // 18.9 MB bf16
    // total ws need: 24,772,608 B

    prep1<<<dim3(2560), 256, 0, stream>>>(cw, style, aw, ab, w_t, wsq, s_buf);
    prep2<<<dim3(6400), 256, 0, stream>>>(x, s_buf, wsq, x_pad, scl);
    conv_mfma<<<dim3(256), 512, 0, stream>>>(w_t, x_pad, scl, out);
}